// Round 6
// baseline (282.890 us; speedup 1.0000x reference)
//
#include <hip/hip_runtime.h>
#include <hip/hip_fp16.h>
#include <math.h>

#define DIM 128

typedef _Float16 half8 __attribute__((ext_vector_type(8)));
typedef _Float16 half2v __attribute__((ext_vector_type(2)));
typedef float floatx4 __attribute__((ext_vector_type(4)));

// Storage column permutation: sigma(c) = (c&15)*8 + (c>>4).
// Applied identically to H, R', T, c0, W2 -> dot product unchanged.
// Chosen so the MFMA epilogue (lane m15 holds cols ct*16+m15, ct=0..7, per row)
// writes 8 consecutive storage halfs per row per lane -> b128 stores.

// ---------------------------------------------------------------------------
// MFMA precompute (single dispatch, 128 rows/block, 256 thr = 4 waves):
//   blocks [0,nHB)        : H  = h          @ W1[  0:128]            -> fp16
//   blocks [nHB,+nRB)     : R' = rel_table  @ W1[128:256] + c0       -> fp16
//   blocks [nHB+nRB,...)  : T  = time_table @ W1[384:512]            -> fp16
// W1 staged in LDS in B-fragment order: each thread builds one 8-half
// fragment (8 strided L2-hot loads) + one ds_write_b128 (conflict-free).
// Epilogue: permuted layout -> 8 b128 stores/thread, contiguous.
// ---------------------------------------------------------------------------
__global__ __launch_bounds__(256) void precompute(
    const float* __restrict__ h, const float* __restrict__ rel,
    const float* __restrict__ tim, const int* __restrict__ qrel,
    const float* __restrict__ W1, const float* __restrict__ b1,
    __half* __restrict__ Hh, __half* __restrict__ Rh, __half* __restrict__ Th,
    int n_nodes, int n_rels, int n_times, int nHB, int nRB)
{
    const int tid = threadIdx.x;
    const int b = blockIdx.x;

    const float* A; __half* Out; int M, k0, row0; bool isR = false;
    if (b < nHB)            { A = h;   Out = Hh; M = n_nodes; k0 = 0;   row0 = b * 128; }
    else if (b < nHB + nRB) { A = rel; Out = Rh; M = n_rels;  k0 = 128; row0 = (b - nHB) * 128; isR = true; }
    else                    { A = tim; Out = Th; M = n_times; k0 = 384; row0 = (b - nHB - nRB) * 128; }

    __shared__ _Float16 fragB[32 * 64 * 8];  // 32 KB: [ct*4+kc][lane][j]
    __shared__ float c0f[DIM];

    // Conflict-free B-fragment staging: thread -> one octet per iter.
    // octet o = (ct*4+kc)*64 + (q*16+n15); element j: W1[k0+kc*32+q*8+j][ct*16+n15]
#pragma unroll
    for (int it = 0; it < 8; ++it) {
        const int o = tid + it * 256;
        const int ctkc = o >> 6, L = o & 63;
        const int ct = ctkc >> 2, kc = ctkc & 3;
        const int q = L >> 4, n15 = L & 15;
        const float* base = W1 + (size_t)(k0 + kc * 32 + q * 8) * DIM + ct * 16 + n15;
        half8 f;
#pragma unroll
        for (int j = 0; j < 8; ++j) f[j] = (_Float16)base[(size_t)j * DIM];
        *(half8*)&fragB[o * 8] = f;
    }
    if (isR && tid < DIM) {  // c0[n] = b1[n] + rel[q] @ W1[256:384]  (orig cols)
        const int q = qrel[0];
        const float* hq = rel + (size_t)q * DIM;
        float s = b1[tid];
        for (int k = 0; k < DIM; ++k)
            s = fmaf(hq[k], W1[(size_t)(256 + k) * DIM + tid], s);
        c0f[tid] = s;
    }
    __syncthreads();

    const int w = tid >> 6;          // wave 0..3 -> rows [row0+w*32, +32)
    const int lane = tid & 63;
    const int m15 = lane & 15, q = lane >> 4;

    const float* aBase[2];
#pragma unroll
    for (int mt = 0; mt < 2; ++mt) {
        int arow = row0 + w * 32 + mt * 16 + m15;
        if (arow >= M) arow = M - 1;     // clamp (stores guarded below)
        aBase[mt] = A + (size_t)arow * DIM + q * 8;
    }

    floatx4 acc[2][8];
#pragma unroll
    for (int mt = 0; mt < 2; ++mt)
#pragma unroll
        for (int ct = 0; ct < 8; ++ct) acc[mt][ct] = (floatx4)0.f;

#pragma unroll
    for (int kc = 0; kc < 4; ++kc) {
        half8 af[2];
#pragma unroll
        for (int mt = 0; mt < 2; ++mt) {
            const float4 a0 = *(const float4*)(aBase[mt] + kc * 32);
            const float4 a1 = *(const float4*)(aBase[mt] + kc * 32 + 4);
            af[mt][0] = (_Float16)a0.x; af[mt][1] = (_Float16)a0.y;
            af[mt][2] = (_Float16)a0.z; af[mt][3] = (_Float16)a0.w;
            af[mt][4] = (_Float16)a1.x; af[mt][5] = (_Float16)a1.y;
            af[mt][6] = (_Float16)a1.z; af[mt][7] = (_Float16)a1.w;
        }
#pragma unroll
        for (int ct = 0; ct < 8; ++ct) {
            const half8 bf = *(half8*)&fragB[(((ct * 4 + kc) * 64) + lane) * 8];
            acc[0][ct] = __builtin_amdgcn_mfma_f32_16x16x32_f16(af[0], bf, acc[0][ct], 0, 0, 0);
            acc[1][ct] = __builtin_amdgcn_mfma_f32_16x16x32_f16(af[1], bf, acc[1][ct], 0, 0, 0);
        }
    }

    // c0 add indexed by ORIG col ct*16+m15 (conflict-free broadcast reads)
    float cadd[8];
#pragma unroll
    for (int ct = 0; ct < 8; ++ct) cadd[ct] = isR ? c0f[ct * 16 + m15] : 0.f;

    // Permuted epilogue: lane writes 8 consecutive storage halfs per row.
    // C/D layout: col = lane&15, row = (lane>>4)*4 + reg  [m89-verified]
#pragma unroll
    for (int mt = 0; mt < 2; ++mt)
#pragma unroll
        for (int r = 0; r < 4; ++r) {
            const int m = row0 + w * 32 + mt * 16 + q * 4 + r;
            if (m < M) {
                half8 hv;
#pragma unroll
                for (int ct = 0; ct < 8; ++ct)
                    hv[ct] = (_Float16)(acc[mt][ct][r] + cadd[ct]);
                *(half8*)(Out + (size_t)m * DIM + m15 * 8) = hv;  // b128, coalesced
            }
        }
}

// ---------------------------------------------------------------------------
// Edge kernel: 1024 threads, R' table in LDS (512 rows x 256B = 128 KB),
// dynamic work queue (32 quads / wave grab). 16 lanes/edge; per iter a wave
// handles 4 quads (one per 16-lane group) = 16 edges; H,T global + R LDS.
// out[e] = sigmoid(dot(relu(H[src]+R'[type]+T[time]), W2) + b2)
// ---------------------------------------------------------------------------
#define RLDS_ROWS 512

__device__ __forceinline__ float edot(uint4 hu, uint4 ru, uint4 tu,
                                      const half2v* __restrict__ w2h) {
    union U { uint4 u; half2v h[4]; };
    U H, R, T; H.u = hu; R.u = ru; T.u = tu;
    const half2v z = (half2v)(_Float16)0.f;
    float p = 0.f;
#pragma unroll
    for (int j = 0; j < 4; ++j) {
        half2v s = H.h[j] + R.h[j] + T.h[j];              // v_pk_add_f16 x2
        s = __builtin_elementwise_max(s, z);              // v_pk_max_f16
#if __has_builtin(__builtin_amdgcn_fdot2)
        p = __builtin_amdgcn_fdot2(s, w2h[j], p, false);  // v_dot2_f32_f16
#else
        p = fmaf((float)s[0], (float)w2h[j][0], p);
        p = fmaf((float)s[1], (float)w2h[j][1], p);
#endif
    }
    return p;
}

__global__ __launch_bounds__(1024) void edge_kernel(
    const int* __restrict__ ei, const int* __restrict__ ety,
    const int* __restrict__ eti,
    const __half* __restrict__ Hh, const __half* __restrict__ Rh,
    const __half* __restrict__ Th,
    const float* __restrict__ W2, const float* __restrict__ b2,
    float* __restrict__ out, int E, int n_rels, int* __restrict__ counter)
{
    __shared__ __half Rlds[RLDS_ROWS * DIM];  // 128 KB

    const int tid = threadIdx.x;
    // Stage R' (plus harmless over-read into T region) as uint4, coalesced.
    {
        const uint4* Rv = (const uint4*)Rh;
        uint4* Lv = (uint4*)Rlds;
        for (int i = tid; i < RLDS_ROWS * (DIM / 8); i += 1024) Lv[i] = Rv[i];
    }
    __syncthreads();

    const int lane = tid & 63;
    const int grp = lane >> 4;   // 0..3
    const int l = lane & 15;
    const int nQuad = (E + 3) >> 2;

    // Permuted W2: lane l's 8 storage halfs map to orig cols jj*16 + l.
    half2v w2h[4];
#pragma unroll
    for (int j = 0; j < 4; ++j) {
        w2h[j][0] = (_Float16)W2[(2 * j) * 16 + l];
        w2h[j][1] = (_Float16)W2[(2 * j + 1) * 16 + l];
    }
    const float b2v = b2[0];

    while (true) {
        int b;
        if (lane == 0) b = atomicAdd(counter, 32);
        b = __shfl(b, 0);
        if (b >= nQuad) break;

        int qd = b + grp;
        int s[4], r[4], t[4];
#pragma unroll
        for (int i = 0; i < 4; ++i) {
            const int e = min(4 * qd + i, E - 1);
            s[i] = ei[e]; r[i] = ety[e]; t[i] = eti[e];
        }

        for (int it = 0; it < 8; ++it) {
            const bool valid = qd < nQuad;
            uint4 hv[4], rv[4], tv[4];
#pragma unroll
            for (int i = 0; i < 4; ++i) {
                hv[i] = ((const uint4*)(Hh + (size_t)s[i] * DIM))[l];
                tv[i] = ((const uint4*)(Th + (size_t)t[i] * DIM))[l];
                if (r[i] < RLDS_ROWS)
                    rv[i] = ((const uint4*)(Rlds + (size_t)r[i] * DIM))[l];
                else
                    rv[i] = ((const uint4*)(Rh + (size_t)r[i] * DIM))[l];
            }
            const int qn = b + (it + 1) * 4 + grp;
            int s2[4], r2[4], t2[4];
            if (it < 7) {
#pragma unroll
                for (int i = 0; i < 4; ++i) {
                    const int e = min(4 * qn + i, E - 1);
                    s2[i] = ei[e]; r2[i] = ety[e]; t2[i] = eti[e];
                }
            }

            float p[4];
#pragma unroll
            for (int i = 0; i < 4; ++i)
                p[i] = edot(hv[i], rv[i], tv[i], w2h);
#pragma unroll
            for (int off = 8; off > 0; off >>= 1) {
#pragma unroll
                for (int i = 0; i < 4; ++i)
                    p[i] += __shfl_down(p[i], off, 16);
            }
            if (valid && l == 0) {
                const int e0 = 4 * qd;
                float4 o;
                o.x = 1.f / (1.f + __expf(-(p[0] + b2v)));
                o.y = 1.f / (1.f + __expf(-(p[1] + b2v)));
                o.z = 1.f / (1.f + __expf(-(p[2] + b2v)));
                o.w = 1.f / (1.f + __expf(-(p[3] + b2v)));
                if (e0 + 3 < E) {
                    *(float4*)(out + e0) = o;
                } else {
                    const float ov[4] = {o.x, o.y, o.z, o.w};
                    for (int i = 0; i < 4 && e0 + i < E; ++i) out[e0 + i] = ov[i];
                }
            }
            if (it < 7) {
#pragma unroll
                for (int i = 0; i < 4; ++i) { s[i] = s2[i]; r[i] = r2[i]; t[i] = t2[i]; }
            }
            qd = qn;
        }
    }
}

extern "C" void kernel_launch(void* const* d_in, const int* in_sizes, int n_in,
                              void* d_out, int out_size, void* d_ws, size_t ws_size,
                              hipStream_t stream) {
    const float* h          = (const float*)d_in[0];
    const int*   edge_index = (const int*)d_in[1];   // [2,E] flat; row 0 = src
    const int*   edge_type  = (const int*)d_in[2];
    const int*   edge_time  = (const int*)d_in[3];
    const int*   query_rel  = (const int*)d_in[4];
    const float* rel_table  = (const float*)d_in[5];
    const float* time_table = (const float*)d_in[6];
    const float* W1         = (const float*)d_in[7]; // [512,128] row-major
    const float* b1         = (const float*)d_in[8];
    const float* W2         = (const float*)d_in[9]; // [128,1]
    const float* b2         = (const float*)d_in[10];
    float* out = (float*)d_out;

    const int n_nodes = in_sizes[0] / DIM;
    const int E       = in_sizes[2];
    const int n_rels  = in_sizes[5] / DIM;
    const int n_times = in_sizes[6] / DIM;

    __half* Hh = (__half*)d_ws;
    __half* Rh = Hh + (size_t)n_nodes * DIM;
    __half* Th = Rh + (size_t)n_rels * DIM;
    // counter after tables, 256B-aligned
    size_t tbl_bytes = ((size_t)(n_nodes + n_rels + n_times) * DIM) * sizeof(__half);
    tbl_bytes = (tbl_bytes + 255) & ~(size_t)255;
    int* counter = (int*)((char*)d_ws + tbl_bytes);

    hipMemsetAsync(counter, 0, sizeof(int), stream);

    const int nHB = (n_nodes + 127) / 128;
    const int nRB = (n_rels + 127) / 128;
    const int nTB = (n_times + 127) / 128;

    precompute<<<nHB + nRB + nTB, 256, 0, stream>>>(
        h, rel_table, time_table, query_rel, W1, b1,
        Hh, Rh, Th, n_nodes, n_rels, n_times, nHB, nRB);

    edge_kernel<<<256, 1024, 0, stream>>>(
        edge_index, edge_type, edge_time, Hh, Rh, Th, W2, b2,
        out, E, n_rels, counter);
}

// Round 7
// 162.735 us; speedup vs baseline: 1.7384x; 1.7384x over previous
//
#include <hip/hip_runtime.h>
#include <hip/hip_fp16.h>
#include <hip/hip_fp8.h>
#include <math.h>

#define DIM 128

typedef _Float16 half8 __attribute__((ext_vector_type(8)));
typedef _Float16 half2v __attribute__((ext_vector_type(2)));
typedef float floatx4 __attribute__((ext_vector_type(4)));

// Storage column permutation: sigma(c) = (c&15)*8 + (c>>4), applied identically
// to H, R', T, W2 -> dot invariant. Lane l of a 16-lane group owns permuted
// positions l*8..l*8+7 == orig cols {i*16+l}. Verified correct in R5/R6 runs.

__device__ __forceinline__ unsigned char enc_fp8(float x) {
    return __hip_fp8_e4m3(x).__x;   // OCP e4m3, RNE
}

// ---------------------------------------------------------------------------
// MFMA precompute (single dispatch, 128 rows/block, 256 thr = 4 waves):
//   blocks [0,nHB)        : H  = h          @ W1[  0:128]            -> fp8 e4m3
//   blocks [nHB,+nRB)     : R' = rel_table  @ W1[128:256] + c0       -> fp16
//   blocks [nHB+nRB,...)  : T  = time_table @ W1[384:512]            -> fp16
// W1 staged in LDS in B-fragment order (one ds_write_b128 per octet,
// conflict-free). Epilogue: permuted layout -> contiguous vector stores.
// ---------------------------------------------------------------------------
__global__ __launch_bounds__(256) void precompute(
    const float* __restrict__ h, const float* __restrict__ rel,
    const float* __restrict__ tim, const int* __restrict__ qrel,
    const float* __restrict__ W1, const float* __restrict__ b1,
    unsigned char* __restrict__ H8, __half* __restrict__ Rh, __half* __restrict__ Th,
    int n_nodes, int n_rels, int n_times, int nHB, int nRB)
{
    const int tid = threadIdx.x;
    const int b = blockIdx.x;

    const float* A; int M, k0, row0; bool isR = false, isH = false;
    __half* Out = nullptr;
    if (b < nHB)            { A = h;   isH = true; M = n_nodes; k0 = 0;   row0 = b * 128; }
    else if (b < nHB + nRB) { A = rel; Out = Rh;   M = n_rels;  k0 = 128; row0 = (b - nHB) * 128; isR = true; }
    else                    { A = tim; Out = Th;   M = n_times; k0 = 384; row0 = (b - nHB - nRB) * 128; }

    __shared__ _Float16 fragB[32 * 64 * 8];  // 32 KB: [ct*4+kc][lane][j]
    __shared__ float c0f[DIM];

    // Conflict-free B-fragment staging: thread -> one octet per iter.
#pragma unroll
    for (int it = 0; it < 8; ++it) {
        const int o = tid + it * 256;
        const int ctkc = o >> 6, L = o & 63;
        const int ct = ctkc >> 2, kc = ctkc & 3;
        const int q = L >> 4, n15 = L & 15;
        const float* base = W1 + (size_t)(k0 + kc * 32 + q * 8) * DIM + ct * 16 + n15;
        half8 f;
#pragma unroll
        for (int j = 0; j < 8; ++j) f[j] = (_Float16)base[(size_t)j * DIM];
        *(half8*)&fragB[o * 8] = f;
    }
    if (isR && tid < DIM) {  // c0[n] = b1[n] + rel[q] @ W1[256:384]  (orig cols)
        const int q = qrel[0];
        const float* hq = rel + (size_t)q * DIM;
        float s = b1[tid];
        for (int k = 0; k < DIM; ++k)
            s = fmaf(hq[k], W1[(size_t)(256 + k) * DIM + tid], s);
        c0f[tid] = s;
    }
    __syncthreads();

    const int w = tid >> 6;          // wave 0..3 -> rows [row0+w*32, +32)
    const int lane = tid & 63;
    const int m15 = lane & 15, q = lane >> 4;

    const float* aBase[2];
#pragma unroll
    for (int mt = 0; mt < 2; ++mt) {
        int arow = row0 + w * 32 + mt * 16 + m15;
        if (arow >= M) arow = M - 1;     // clamp (stores guarded below)
        aBase[mt] = A + (size_t)arow * DIM + q * 8;
    }

    floatx4 acc[2][8];
#pragma unroll
    for (int mt = 0; mt < 2; ++mt)
#pragma unroll
        for (int ct = 0; ct < 8; ++ct) acc[mt][ct] = (floatx4)0.f;

#pragma unroll
    for (int kc = 0; kc < 4; ++kc) {
        half8 af[2];
#pragma unroll
        for (int mt = 0; mt < 2; ++mt) {
            const float4 a0 = *(const float4*)(aBase[mt] + kc * 32);
            const float4 a1 = *(const float4*)(aBase[mt] + kc * 32 + 4);
            af[mt][0] = (_Float16)a0.x; af[mt][1] = (_Float16)a0.y;
            af[mt][2] = (_Float16)a0.z; af[mt][3] = (_Float16)a0.w;
            af[mt][4] = (_Float16)a1.x; af[mt][5] = (_Float16)a1.y;
            af[mt][6] = (_Float16)a1.z; af[mt][7] = (_Float16)a1.w;
        }
#pragma unroll
        for (int ct = 0; ct < 8; ++ct) {
            const half8 bf = *(half8*)&fragB[(((ct * 4 + kc) * 64) + lane) * 8];
            acc[0][ct] = __builtin_amdgcn_mfma_f32_16x16x32_f16(af[0], bf, acc[0][ct], 0, 0, 0);
            acc[1][ct] = __builtin_amdgcn_mfma_f32_16x16x32_f16(af[1], bf, acc[1][ct], 0, 0, 0);
        }
    }

    float cadd[8];
#pragma unroll
    for (int ct = 0; ct < 8; ++ct) cadd[ct] = isR ? c0f[ct * 16 + m15] : 0.f;

    // Permuted epilogue. C/D layout: col = lane&15, row = (lane>>4)*4 + reg.
#pragma unroll
    for (int mt = 0; mt < 2; ++mt)
#pragma unroll
        for (int r = 0; r < 4; ++r) {
            const int m = row0 + w * 32 + mt * 16 + q * 4 + r;
            if (m < M) {
                if (isH) {
                    union { uint2 u; unsigned char bb[8]; } pk;
#pragma unroll
                    for (int ct = 0; ct < 8; ++ct)
                        pk.bb[ct] = enc_fp8(acc[mt][ct][r]);
                    *(uint2*)(H8 + (size_t)m * DIM + m15 * 8) = pk.u;  // b64, coalesced
                } else {
                    half8 hv;
#pragma unroll
                    for (int ct = 0; ct < 8; ++ct)
                        hv[ct] = (_Float16)(acc[mt][ct][r] + cadd[ct]);
                    *(half8*)(Out + (size_t)m * DIM + m15 * 8) = hv;   // b128, coalesced
                }
            }
        }
}

// ---------------------------------------------------------------------------
// Edge kernel (R5 structure): persistent grid-stride; 16 lanes/group, 4
// edges/iter, 12 gathers in flight + index prefetch. H fp8 (uint2/lane),
// R'/T fp16 (uint4/lane). Packed fp16 adds/relu + v_dot2_f32_f16.
// out[e] = sigmoid(dot(relu(H[src]+R'[type]+T[time]), W2) + b2)
// ---------------------------------------------------------------------------
__device__ __forceinline__ half2v fp8x2_to_h2(unsigned u16) {
#if __has_builtin(__builtin_amdgcn_cvt_pk_f16_fp8)
    auto c = __builtin_amdgcn_cvt_pk_f16_fp8((short)u16);
    half2v r; r[0] = c[0]; r[1] = c[1];
    return r;
#else
    auto f = __builtin_amdgcn_cvt_pk_f32_fp8((int)u16, false);
    half2v r; r[0] = (_Float16)f[0]; r[1] = (_Float16)f[1];
    return r;
#endif
}

__device__ __forceinline__ float edot(uint2 hu, uint4 ru, uint4 tu,
                                      const half2v* __restrict__ w2h) {
    union U { uint4 u; half2v h[4]; };
    U R, T; R.u = ru; T.u = tu;
    const half2v z = (half2v)(_Float16)0.f;
    const unsigned hw[4] = {hu.x & 0xffffu, hu.x >> 16, hu.y & 0xffffu, hu.y >> 16};
    float p = 0.f;
#pragma unroll
    for (int j = 0; j < 4; ++j) {
        const half2v hh = fp8x2_to_h2(hw[j]);
        half2v s = hh + R.h[j] + T.h[j];                  // v_pk_add_f16 x2
        s = __builtin_elementwise_max(s, z);              // v_pk_max_f16
#if __has_builtin(__builtin_amdgcn_fdot2)
        p = __builtin_amdgcn_fdot2(s, w2h[j], p, false);  // v_dot2_f32_f16
#else
        p = fmaf((float)s[0], (float)w2h[j][0], p);
        p = fmaf((float)s[1], (float)w2h[j][1], p);
#endif
    }
    return p;
}

__global__ __launch_bounds__(256) void edge_kernel(
    const int* __restrict__ ei, const int* __restrict__ ety,
    const int* __restrict__ eti,
    const unsigned char* __restrict__ H8, const __half* __restrict__ Rh,
    const __half* __restrict__ Th,
    const float* __restrict__ W2, const float* __restrict__ b2,
    float* __restrict__ out, int E, int nGrpTotal)
{
    const int tid = threadIdx.x;
    const int l = tid & 15;
    int g = blockIdx.x * 16 + (tid >> 4);
    const int nQuad = (E + 3) >> 2;
    if (g >= nQuad) return;

    // Permuted W2: lane l's 8 storage positions map to orig cols i*16 + l.
    half2v w2h[4];
#pragma unroll
    for (int j = 0; j < 4; ++j) {
        w2h[j][0] = (_Float16)W2[(2 * j) * 16 + l];
        w2h[j][1] = (_Float16)W2[(2 * j + 1) * 16 + l];
    }
    const float b2v = b2[0];

    int s[4], r[4], t[4];
#pragma unroll
    for (int i = 0; i < 4; ++i) {
        const int e = min(4 * g + i, E - 1);
        s[i] = ei[e]; r[i] = ety[e]; t[i] = eti[e];
    }

    while (true) {
        const int gn = g + nGrpTotal;
        // 12 gathers in flight
        uint2 hv[4]; uint4 rv[4], tv[4];
#pragma unroll
        for (int i = 0; i < 4; ++i) {
            hv[i] = ((const uint2*)(H8 + (size_t)s[i] * DIM))[l];
            rv[i] = ((const uint4*)(Rh + (size_t)r[i] * DIM))[l];
            tv[i] = ((const uint4*)(Th + (size_t)t[i] * DIM))[l];
        }
        if (gn < nQuad) {  // prefetch next indices while gathers land
#pragma unroll
            for (int i = 0; i < 4; ++i) {
                const int e = min(4 * gn + i, E - 1);
                s[i] = ei[e]; r[i] = ety[e]; t[i] = eti[e];
            }
        }
        float p[4];
#pragma unroll
        for (int i = 0; i < 4; ++i)
            p[i] = edot(hv[i], rv[i], tv[i], w2h);
#pragma unroll
        for (int off = 8; off > 0; off >>= 1) {
#pragma unroll
            for (int i = 0; i < 4; ++i)
                p[i] += __shfl_down(p[i], off, 16);
        }
        if (l == 0) {
            const int e0 = 4 * g;
            float4 o;
            o.x = 1.f / (1.f + __expf(-(p[0] + b2v)));
            o.y = 1.f / (1.f + __expf(-(p[1] + b2v)));
            o.z = 1.f / (1.f + __expf(-(p[2] + b2v)));
            o.w = 1.f / (1.f + __expf(-(p[3] + b2v)));
            if (e0 + 3 < E) {
                *(float4*)(out + e0) = o;
            } else {
                const float ov[4] = {o.x, o.y, o.z, o.w};
                for (int i = 0; i < 4 && e0 + i < E; ++i) out[e0 + i] = ov[i];
            }
        }
        if (gn >= nQuad) break;
        g = gn;
    }
}

extern "C" void kernel_launch(void* const* d_in, const int* in_sizes, int n_in,
                              void* d_out, int out_size, void* d_ws, size_t ws_size,
                              hipStream_t stream) {
    const float* h          = (const float*)d_in[0];
    const int*   edge_index = (const int*)d_in[1];   // [2,E] flat; row 0 = src
    const int*   edge_type  = (const int*)d_in[2];
    const int*   edge_time  = (const int*)d_in[3];
    const int*   query_rel  = (const int*)d_in[4];
    const float* rel_table  = (const float*)d_in[5];
    const float* time_table = (const float*)d_in[6];
    const float* W1         = (const float*)d_in[7]; // [512,128] row-major
    const float* b1         = (const float*)d_in[8];
    const float* W2         = (const float*)d_in[9]; // [128,1]
    const float* b2         = (const float*)d_in[10];
    float* out = (float*)d_out;

    const int n_nodes = in_sizes[0] / DIM;
    const int E       = in_sizes[2];
    const int n_rels  = in_sizes[5] / DIM;
    const int n_times = in_sizes[6] / DIM;

    unsigned char* H8 = (unsigned char*)d_ws;                    // n_nodes*128 B
    __half* Rh = (__half*)(H8 + ((size_t)n_nodes * DIM + 255 & ~(size_t)255));
    __half* Th = Rh + (size_t)n_rels * DIM;

    const int nHB = (n_nodes + 127) / 128;
    const int nRB = (n_rels + 127) / 128;
    const int nTB = (n_times + 127) / 128;

    precompute<<<nHB + nRB + nTB, 256, 0, stream>>>(
        h, rel_table, time_table, query_rel, W1, b1,
        H8, Rh, Th, n_nodes, n_rels, n_times, nHB, nRB);

    const int nBlk = 2048;  // persistent grid-stride
    edge_kernel<<<nBlk, 256, 0, stream>>>(
        edge_index, edge_type, edge_time, H8, Rh, Th, W2, b2,
        out, E, nBlk * 16);
}

// Round 8
// 157.314 us; speedup vs baseline: 1.7983x; 1.0345x over previous
//
#include <hip/hip_runtime.h>
#include <hip/hip_fp16.h>
#include <hip/hip_fp8.h>
#include <math.h>

#define DIM 128

typedef _Float16 half8 __attribute__((ext_vector_type(8)));
typedef _Float16 half2v __attribute__((ext_vector_type(2)));
typedef float floatx4 __attribute__((ext_vector_type(4)));

// Storage column permutation: sigma(c) = (c&15)*8 + (c>>4), applied identically
// to H, R', T, W2 -> dot invariant. Lane l of a 16-lane group owns permuted
// positions l*8..l*8+7 == orig cols {i*16+l}. Verified in R5-R7 runs.

// ---------------------------------------------------------------------------
// MFMA precompute (single dispatch, 128 rows/block, 256 thr = 4 waves):
//   blocks [0,nHB)        : H  = h          @ W1[  0:128]            -> fp8 e4m3
//   blocks [nHB,+nRB)     : R' = rel_table  @ W1[128:256] + c0       -> fp16
//   blocks [nHB+nRB,...)  : T  = time_table @ W1[384:512]            -> fp16
// W1 staged in LDS in B-fragment order (one ds_write_b128 per octet,
// conflict-free). Epilogue: permuted layout -> contiguous vector stores;
// fp8 encode via HW v_cvt_pk_fp8_f32 (4 inst / 8 bytes).
// ---------------------------------------------------------------------------
__global__ __launch_bounds__(256) void precompute(
    const float* __restrict__ h, const float* __restrict__ rel,
    const float* __restrict__ tim, const int* __restrict__ qrel,
    const float* __restrict__ W1, const float* __restrict__ b1,
    unsigned char* __restrict__ H8, __half* __restrict__ Rh, __half* __restrict__ Th,
    int n_nodes, int n_rels, int n_times, int nHB, int nRB)
{
    const int tid = threadIdx.x;
    const int b = blockIdx.x;

    const float* A; int M, k0, row0; bool isR = false, isH = false;
    __half* Out = nullptr;
    if (b < nHB)            { A = h;   isH = true; M = n_nodes; k0 = 0;   row0 = b * 128; }
    else if (b < nHB + nRB) { A = rel; Out = Rh;   M = n_rels;  k0 = 128; row0 = (b - nHB) * 128; isR = true; }
    else                    { A = tim; Out = Th;   M = n_times; k0 = 384; row0 = (b - nHB - nRB) * 128; }

    __shared__ _Float16 fragB[32 * 64 * 8];  // 32 KB: [ct*4+kc][lane][j]
    __shared__ float c0f[DIM];

    // Conflict-free B-fragment staging: thread -> one octet per iter.
#pragma unroll
    for (int it = 0; it < 8; ++it) {
        const int o = tid + it * 256;
        const int ctkc = o >> 6, L = o & 63;
        const int ct = ctkc >> 2, kc = ctkc & 3;
        const int q = L >> 4, n15 = L & 15;
        const float* base = W1 + (size_t)(k0 + kc * 32 + q * 8) * DIM + ct * 16 + n15;
        half8 f;
#pragma unroll
        for (int j = 0; j < 8; ++j) f[j] = (_Float16)base[(size_t)j * DIM];
        *(half8*)&fragB[o * 8] = f;
    }
    if (isR && tid < DIM) {  // c0[n] = b1[n] + rel[q] @ W1[256:384]  (orig cols)
        const int q = qrel[0];
        const float* hq = rel + (size_t)q * DIM;
        float s = b1[tid];
        for (int k = 0; k < DIM; ++k)
            s = fmaf(hq[k], W1[(size_t)(256 + k) * DIM + tid], s);
        c0f[tid] = s;
    }
    __syncthreads();

    const int w = tid >> 6;          // wave 0..3 -> rows [row0+w*32, +32)
    const int lane = tid & 63;
    const int m15 = lane & 15, q = lane >> 4;

    const float* aBase[2];
#pragma unroll
    for (int mt = 0; mt < 2; ++mt) {
        int arow = row0 + w * 32 + mt * 16 + m15;
        if (arow >= M) arow = M - 1;     // clamp (stores guarded below)
        aBase[mt] = A + (size_t)arow * DIM + q * 8;
    }

    floatx4 acc[2][8];
#pragma unroll
    for (int mt = 0; mt < 2; ++mt)
#pragma unroll
        for (int ct = 0; ct < 8; ++ct) acc[mt][ct] = (floatx4)0.f;

#pragma unroll
    for (int kc = 0; kc < 4; ++kc) {
        half8 af[2];
#pragma unroll
        for (int mt = 0; mt < 2; ++mt) {
            const float4 a0 = *(const float4*)(aBase[mt] + kc * 32);
            const float4 a1 = *(const float4*)(aBase[mt] + kc * 32 + 4);
            af[mt][0] = (_Float16)a0.x; af[mt][1] = (_Float16)a0.y;
            af[mt][2] = (_Float16)a0.z; af[mt][3] = (_Float16)a0.w;
            af[mt][4] = (_Float16)a1.x; af[mt][5] = (_Float16)a1.y;
            af[mt][6] = (_Float16)a1.z; af[mt][7] = (_Float16)a1.w;
        }
#pragma unroll
        for (int ct = 0; ct < 8; ++ct) {
            const half8 bf = *(half8*)&fragB[(((ct * 4 + kc) * 64) + lane) * 8];
            acc[0][ct] = __builtin_amdgcn_mfma_f32_16x16x32_f16(af[0], bf, acc[0][ct], 0, 0, 0);
            acc[1][ct] = __builtin_amdgcn_mfma_f32_16x16x32_f16(af[1], bf, acc[1][ct], 0, 0, 0);
        }
    }

    float cadd[8];
#pragma unroll
    for (int ct = 0; ct < 8; ++ct) cadd[ct] = isR ? c0f[ct * 16 + m15] : 0.f;

    // Permuted epilogue. C/D layout: col = lane&15, row = (lane>>4)*4 + reg.
#pragma unroll
    for (int mt = 0; mt < 2; ++mt)
#pragma unroll
        for (int r = 0; r < 4; ++r) {
            const int m = row0 + w * 32 + mt * 16 + q * 4 + r;
            if (m < M) {
                if (isH) {
                    uint2 pk;
#if __has_builtin(__builtin_amdgcn_cvt_pk_fp8_f32)
                    int w0 = 0, w1 = 0;
                    w0 = __builtin_amdgcn_cvt_pk_fp8_f32(acc[mt][0][r], acc[mt][1][r], w0, false);
                    w0 = __builtin_amdgcn_cvt_pk_fp8_f32(acc[mt][2][r], acc[mt][3][r], w0, true);
                    w1 = __builtin_amdgcn_cvt_pk_fp8_f32(acc[mt][4][r], acc[mt][5][r], w1, false);
                    w1 = __builtin_amdgcn_cvt_pk_fp8_f32(acc[mt][6][r], acc[mt][7][r], w1, true);
                    pk.x = (unsigned)w0; pk.y = (unsigned)w1;
#else
                    union { uint2 u; unsigned char bb[8]; } pu;
#pragma unroll
                    for (int ct = 0; ct < 8; ++ct)
                        pu.bb[ct] = __hip_fp8_e4m3(acc[mt][ct][r]).__x;
                    pk = pu.u;
#endif
                    *(uint2*)(H8 + (size_t)m * DIM + m15 * 8) = pk;    // b64, coalesced
                } else {
                    half8 hv;
#pragma unroll
                    for (int ct = 0; ct < 8; ++ct)
                        hv[ct] = (_Float16)(acc[mt][ct][r] + cadd[ct]);
                    *(half8*)(Out + (size_t)m * DIM + m15 * 8) = hv;   // b128, coalesced
                }
            }
        }
}

// ---------------------------------------------------------------------------
// Edge kernel (R5 structure): persistent grid-stride; 16 lanes/group, 4
// edges/iter, 12 gathers in flight + index prefetch. H fp8 (uint2/lane),
// R'/T fp16 (uint4/lane). Packed fp16 adds/relu + v_dot2_f32_f16.
// out[e] = sigmoid(dot(relu(H[src]+R'[type]+T[time]), W2) + b2)
// ---------------------------------------------------------------------------
__device__ __forceinline__ half2v fp8x2_to_h2(unsigned u16) {
#if __has_builtin(__builtin_amdgcn_cvt_pk_f16_fp8)
    auto c = __builtin_amdgcn_cvt_pk_f16_fp8((short)u16);
    half2v r; r[0] = c[0]; r[1] = c[1];
    return r;
#else
    auto f = __builtin_amdgcn_cvt_pk_f32_fp8((int)u16, false);
    half2v r; r[0] = (_Float16)f[0]; r[1] = (_Float16)f[1];
    return r;
#endif
}

__device__ __forceinline__ float edot(uint2 hu, uint4 ru, uint4 tu,
                                      const half2v* __restrict__ w2h) {
    union U { uint4 u; half2v h[4]; };
    U R, T; R.u = ru; T.u = tu;
    const half2v z = (half2v)(_Float16)0.f;
    const unsigned hw[4] = {hu.x & 0xffffu, hu.x >> 16, hu.y & 0xffffu, hu.y >> 16};
    float p = 0.f;
#pragma unroll
    for (int j = 0; j < 4; ++j) {
        const half2v hh = fp8x2_to_h2(hw[j]);
        half2v s = hh + R.h[j] + T.h[j];                  // v_pk_add_f16 x2
        s = __builtin_elementwise_max(s, z);              // v_pk_max_f16
#if __has_builtin(__builtin_amdgcn_fdot2)
        p = __builtin_amdgcn_fdot2(s, w2h[j], p, false);  // v_dot2_f32_f16
#else
        p = fmaf((float)s[0], (float)w2h[j][0], p);
        p = fmaf((float)s[1], (float)w2h[j][1], p);
#endif
    }
    return p;
}

__global__ __launch_bounds__(256) void edge_kernel(
    const int* __restrict__ ei, const int* __restrict__ ety,
    const int* __restrict__ eti,
    const unsigned char* __restrict__ H8, const __half* __restrict__ Rh,
    const __half* __restrict__ Th,
    const float* __restrict__ W2, const float* __restrict__ b2,
    float* __restrict__ out, int E, int nGrpTotal)
{
    const int tid = threadIdx.x;
    const int l = tid & 15;
    int g = blockIdx.x * 16 + (tid >> 4);
    const int nQuad = (E + 3) >> 2;
    if (g >= nQuad) return;

    // Permuted W2: lane l's 8 storage positions map to orig cols i*16 + l.
    half2v w2h[4];
#pragma unroll
    for (int j = 0; j < 4; ++j) {
        w2h[j][0] = (_Float16)W2[(2 * j) * 16 + l];
        w2h[j][1] = (_Float16)W2[(2 * j + 1) * 16 + l];
    }
    const float b2v = b2[0];
    const bool exact = (E & 3) == 0;

    int s[4], r[4], t[4];
    {
        const int e0 = 4 * g;
        if (exact || e0 + 3 < E) {
#pragma unroll
            for (int i = 0; i < 4; ++i) { s[i] = ei[e0 + i]; r[i] = ety[e0 + i]; t[i] = eti[e0 + i]; }
        } else {
#pragma unroll
            for (int i = 0; i < 4; ++i) {
                const int e = min(e0 + i, E - 1);
                s[i] = ei[e]; r[i] = ety[e]; t[i] = eti[e];
            }
        }
    }

    while (true) {
        const int gn = g + nGrpTotal;
        // 12 gathers in flight
        uint2 hv[4]; uint4 rv[4], tv[4];
#pragma unroll
        for (int i = 0; i < 4; ++i) {
            hv[i] = ((const uint2*)(H8 + (size_t)s[i] * DIM))[l];
            rv[i] = ((const uint4*)(Rh + (size_t)r[i] * DIM))[l];
            tv[i] = ((const uint4*)(Th + (size_t)t[i] * DIM))[l];
        }
        if (gn < nQuad) {  // prefetch next indices while gathers land
            const int e0 = 4 * gn;
            if (exact || e0 + 3 < E) {
#pragma unroll
                for (int i = 0; i < 4; ++i) { s[i] = ei[e0 + i]; r[i] = ety[e0 + i]; t[i] = eti[e0 + i]; }
            } else {
#pragma unroll
                for (int i = 0; i < 4; ++i) {
                    const int e = min(e0 + i, E - 1);
                    s[i] = ei[e]; r[i] = ety[e]; t[i] = eti[e];
                }
            }
        }
        float p[4];
#pragma unroll
        for (int i = 0; i < 4; ++i)
            p[i] = edot(hv[i], rv[i], tv[i], w2h);
#pragma unroll
        for (int off = 8; off > 0; off >>= 1) {
#pragma unroll
            for (int i = 0; i < 4; ++i)
                p[i] += __shfl_down(p[i], off, 16);
        }
        if (l == 0) {
            const int e0 = 4 * g;
            float4 o;
            o.x = 1.f / (1.f + __expf(-(p[0] + b2v)));
            o.y = 1.f / (1.f + __expf(-(p[1] + b2v)));
            o.z = 1.f / (1.f + __expf(-(p[2] + b2v)));
            o.w = 1.f / (1.f + __expf(-(p[3] + b2v)));
            if (e0 + 3 < E) {
                *(float4*)(out + e0) = o;
            } else {
                const float ov[4] = {o.x, o.y, o.z, o.w};
                for (int i = 0; i < 4 && e0 + i < E; ++i) out[e0 + i] = ov[i];
            }
        }
        if (gn >= nQuad) break;
        g = gn;
    }
}

extern "C" void kernel_launch(void* const* d_in, const int* in_sizes, int n_in,
                              void* d_out, int out_size, void* d_ws, size_t ws_size,
                              hipStream_t stream) {
    const float* h          = (const float*)d_in[0];
    const int*   edge_index = (const int*)d_in[1];   // [2,E] flat; row 0 = src
    const int*   edge_type  = (const int*)d_in[2];
    const int*   edge_time  = (const int*)d_in[3];
    const int*   query_rel  = (const int*)d_in[4];
    const float* rel_table  = (const float*)d_in[5];
    const float* time_table = (const float*)d_in[6];
    const float* W1         = (const float*)d_in[7]; // [512,128] row-major
    const float* b1         = (const float*)d_in[8];
    const float* W2         = (const float*)d_in[9]; // [128,1]
    const float* b2         = (const float*)d_in[10];
    float* out = (float*)d_out;

    const int n_nodes = in_sizes[0] / DIM;
    const int E       = in_sizes[2];
    const int n_rels  = in_sizes[5] / DIM;
    const int n_times = in_sizes[6] / DIM;

    unsigned char* H8 = (unsigned char*)d_ws;                    // n_nodes*128 B
    __half* Rh = (__half*)(H8 + (((size_t)n_nodes * DIM + 255) & ~(size_t)255));
    __half* Th = Rh + (size_t)n_rels * DIM;

    const int nHB = (n_nodes + 127) / 128;
    const int nRB = (n_rels + 127) / 128;
    const int nTB = (n_times + 127) / 128;

    precompute<<<nHB + nRB + nTB, 256, 0, stream>>>(
        h, rel_table, time_table, query_rel, W1, b1,
        H8, Rh, Th, n_nodes, n_rels, n_times, nHB, nRB);

    const int nBlk = 4096;  // 2x oversubscription, grid-stride
    edge_kernel<<<nBlk, 256, 0, stream>>>(
        edge_index, edge_type, edge_time, H8, Rh, Th, W2, b2,
        out, E, nBlk * 16);
}